// Round 1
// baseline (111.504 us; speedup 1.0000x reference)
//
#include <hip/hip_runtime.h>

#define NDIM 2048
#define BDIM 16384

// Kernel 1: build cos/sin table in workspace. cs[0..NDIM) = cos, cs[NDIM..2*NDIM) = sin.
__global__ __launch_bounds__(256) void cs_table_kernel(const float* __restrict__ phases,
                                                       float* __restrict__ cs) {
    int j = blockIdx.x * blockDim.x + threadIdx.x;
    if (j < NDIM) {
        float p = phases[j];
        float s, c;
        sincosf(p, &s, &c);   // accurate sincos; only 2048 lanes total
        cs[j] = c;
        cs[NDIM + j] = s;
    }
}

// Kernel 2: vectorized elementwise complex rotation.
// out_real[i,j] = xr*c - xi*s ; out_imag[i,j] = xr*s + xi*c
__global__ __launch_bounds__(256) void phase_rot_kernel(const float4* __restrict__ xr,
                                                        const float4* __restrict__ xi,
                                                        const float* __restrict__ cs,
                                                        float4* __restrict__ out_real,
                                                        float4* __restrict__ out_imag,
                                                        long nvec) {
    const float4* __restrict__ c4 = (const float4*)cs;
    const float4* __restrict__ s4 = (const float4*)(cs + NDIM);
    const int colmask = (NDIM / 4) - 1;  // NDIM pow2; float4 stays within a row
    long stride = (long)gridDim.x * blockDim.x;
    for (long v = (long)blockIdx.x * blockDim.x + threadIdx.x; v < nvec; v += stride) {
        int jv = (int)(v & colmask);
        float4 r = xr[v];
        float4 i = xi[v];
        float4 c = c4[jv];
        float4 s = s4[jv];
        float4 orr, oii;
        orr.x = r.x * c.x - i.x * s.x;  oii.x = r.x * s.x + i.x * c.x;
        orr.y = r.y * c.y - i.y * s.y;  oii.y = r.y * s.y + i.y * c.y;
        orr.z = r.z * c.z - i.z * s.z;  oii.z = r.z * s.z + i.z * c.z;
        orr.w = r.w * c.w - i.w * s.w;  oii.w = r.w * s.w + i.w * c.w;
        out_real[v] = orr;
        out_imag[v] = oii;
    }
}

extern "C" void kernel_launch(void* const* d_in, const int* in_sizes, int n_in,
                              void* d_out, int out_size, void* d_ws, size_t ws_size,
                              hipStream_t stream) {
    const float* x_real = (const float*)d_in[0];
    const float* x_imag = (const float*)d_in[1];
    const float* phases = (const float*)d_in[2];
    float* out = (float*)d_out;
    float* cs = (float*)d_ws;  // 2*NDIM floats = 16 KB

    // 1) cos/sin table
    cs_table_kernel<<<(NDIM + 255) / 256, 256, 0, stream>>>(phases, cs);

    // 2) main elementwise pass
    const long nvec = (long)BDIM * NDIM / 4;            // 8,388,608 float4s
    const long plane = (long)BDIM * NDIM;               // elements per output plane
    float4* out_real = (float4*)out;
    float4* out_imag = (float4*)(out + plane);
    int blocks = 2048;  // grid-stride; ~16 float4 per thread
    phase_rot_kernel<<<blocks, 256, 0, stream>>>(
        (const float4*)x_real, (const float4*)x_imag, cs, out_real, out_imag, nvec);
}

// Round 2
// 87.026 us; speedup vs baseline: 1.2813x; 1.2813x over previous
//
#include <hip/hip_runtime.h>

#define NDIM 2048
#define BDIM 16384

typedef float f32x4 __attribute__((ext_vector_type(4)));

// One fused kernel. Grid stride (2048 blocks x 256 threads = 524288 float4s)
// is an exact multiple of the row width (NDIM/4 = 512 float4s), so each
// thread touches ONE fixed column group for all its iterations:
// compute sincos once per thread, then stream 16 rows.
__global__ __launch_bounds__(256) void phase_rot_fused(
    const f32x4* __restrict__ xr, const f32x4* __restrict__ xi,
    const float* __restrict__ phases,
    f32x4* __restrict__ out_r, f32x4* __restrict__ out_i)
{
    constexpr int COLV   = NDIM / 4;          // 512 float4s per row
    constexpr long STRIDE = 2048L * 256L;     // 524288 float4s (= 1024 rows)
    constexpr int ITERS  = (long)BDIM * COLV / STRIDE;  // 16
    static_assert((long)BDIM * COLV == STRIDE * ITERS, "exact tiling");
    static_assert(STRIDE % COLV == 0, "column invariant per thread");

    const long tid = (long)blockIdx.x * 256 + threadIdx.x;
    const int jv = (int)(tid & (COLV - 1));   // this thread's column (float4 units)

    // per-thread sincos for its 4 columns, computed once (8 KB phases -> L1/L2 hit)
    const f32x4 p = ((const f32x4*)phases)[jv];
    float c0, c1, c2, c3, s0, s1, s2, s3;
    sincosf(p.x, &s0, &c0);
    sincosf(p.y, &s1, &c1);
    sincosf(p.z, &s2, &c2);
    sincosf(p.w, &s3, &c3);
    const f32x4 c = {c0, c1, c2, c3};
    const f32x4 s = {s0, s1, s2, s3};

    long v = tid;
    #pragma unroll 4
    for (int k = 0; k < ITERS; ++k) {
        f32x4 r = xr[v];
        f32x4 i = xi[v];
        f32x4 orr = r * c - i * s;
        f32x4 oii = r * s + i * c;
        __builtin_nontemporal_store(orr, &out_r[v]);
        __builtin_nontemporal_store(oii, &out_i[v]);
        v += STRIDE;
    }
}

extern "C" void kernel_launch(void* const* d_in, const int* in_sizes, int n_in,
                              void* d_out, int out_size, void* d_ws, size_t ws_size,
                              hipStream_t stream) {
    const f32x4* x_real = (const f32x4*)d_in[0];
    const f32x4* x_imag = (const f32x4*)d_in[1];
    const float* phases = (const float*)d_in[2];
    float* out = (float*)d_out;

    const long plane = (long)BDIM * NDIM;     // elements per output plane
    f32x4* out_r = (f32x4*)out;
    f32x4* out_i = (f32x4*)(out + plane);

    phase_rot_fused<<<2048, 256, 0, stream>>>(x_real, x_imag, phases, out_r, out_i);
}